// Round 5
// baseline (159.231 us; speedup 1.0000x reference)
//
#include <hip/hip_runtime.h>

// HQQ 4-bit dequant + linear (Llama-7B up-proj, decode: 8 tokens)
// OUT=11008, IN=4096, GS=64, G=704512, OC=172 (=G/IN; OUT=64*OC)
// W_q: [32, G] int32 (one byte per word: hi nibble -> unpacked row rq,
//      lo nibble -> row rq+32 of the [64, G] tensor)
// Mapping: W_r[o, i] with r=o/172, oc=o%172, g=oc*4096+i.
//
// R8 = R7 resubmission (R7 bench failed: GPUAcquisitionTimeout, no data).
// R7 theory: R5/R6 4-wave blocks ran in CU-level lockstep (barrier-phased:
// all co-resident blocks issue together, then compute with ~0 bytes in
// flight -> ~50% memory duty). Fix: single-wave blocks, no barriers, no
// LDS staging. Wq + scale/zero double-buffered in REGISTERS one iter
// ahead; x read straight from L1/L2 (128 KB resident, shared by the 16
// XCD-co-located sibling waves). 16 independent waves/CU, all at
// different phases -> continuous issue. Compiler's per-register counted
// vmcnt does the scheduling; zero inline asm.
//  - bid decode: xcd=bid&7, 86 chunks/XCD -> a chunk's 16 sibs share one
//    XCD L2 (s/z fetched once from HBM, read 16x from L2).
//  - Tail: 8 KB per-wave LDS transpose (single-wave __syncthreads is
//    ~free), coalesced 32-float ws store; coalesced-read reduce kernel.

#define OUT_ 11008
#define IN_ 4096
#define G_ 704512
#define OC_ 172
#define KS 4
#define KC (IN_ / KS)       // 1024
#define ITERS (KC / 256)    // 4
#define NCHUNK (OC_ * KS)   // 688 chunks; 688/8 = 86 per XCD
#define NB (NCHUNK * 16)    // 11008 single-wave blocks

__global__ __launch_bounds__(64, 4)
void hqq_gemv(const int* __restrict__ Wq, const float* __restrict__ scale,
              const float* __restrict__ zero, const float* __restrict__ x,
              float* __restrict__ ws) {
    __shared__ float red[32 * 64];             // 8 KB transpose scratch

    const int lane = threadIdx.x;              // 0..63
    const int bid  = blockIdx.x;
    const int xcd  = bid & 7;                  // HW round-robin XCD
    const int i_   = bid >> 3;                 // 0..1375
    const int c    = xcd * (NCHUNK / 8) + (i_ >> 4);  // chunk 0..687
    const int sib  = i_ & 15;                  // 16 siblings share chunk c
    const int oc   = c >> 2;                   // 0..171
    const int ks   = c & 3;                    // 0..3
    const int rq0  = sib * 2;                  // packed rows rq0, rq0+1

    const int kbase = ks * KC;
    const int gb    = oc * IN_ + kbase;

    const int*   __restrict__ wqA = Wq + (long)rq0 * G_ + gb + lane * 4;
    const int*   __restrict__ wqB = wqA + G_;
    const float* __restrict__ sp  = scale + gb + lane * 4;
    const float* __restrict__ zp  = zero  + gb + lane * 4;
    const float* __restrict__ xp  = x + kbase + lane * 4;

    // ---- register double-buffer: iter 0 operands in flight immediately ----
    int4   qa[2], qb[2];
    float4 sv[2], zv[2];
    qa[0] = *(const int4*)(wqA);
    qb[0] = *(const int4*)(wqB);
    sv[0] = *(const float4*)(sp);
    zv[0] = *(const float4*)(zp);

    // acc[0]=hi(rq0) acc[1]=lo(rq0) acc[2]=hi(rq0+1) acc[3]=lo(rq0+1)
    float acc[4][8];
#pragma unroll
    for (int r = 0; r < 4; ++r)
#pragma unroll
        for (int b = 0; b < 8; ++b) acc[r][b] = 0.f;

#pragma unroll
    for (int it = 0; it < ITERS; ++it) {       // fully unrolled: static idx
        const int cur = it & 1, nxt = cur ^ 1;
        if (it + 1 < ITERS) {                  // prefetch next iter's operands
            qa[nxt] = *(const int4*)(wqA + (it + 1) * 256);
            qb[nxt] = *(const int4*)(wqB + (it + 1) * 256);
            sv[nxt] = *(const float4*)(sp + (it + 1) * 256);
            zv[nxt] = *(const float4*)(zp + (it + 1) * 256);
        }
        const float4 s4 = sv[cur];
        const float4 z4 = zv[cur];
        const float ss[4] = {s4.x, s4.y, s4.z, s4.w};
        const float zs[4] = {-z4.x * s4.x, -z4.y * s4.y, -z4.z * s4.z, -z4.w * s4.w};
        const int qsA[4] = {qa[cur].x, qa[cur].y, qa[cur].z, qa[cur].w};
        const int qsB[4] = {qb[cur].x, qb[cur].y, qb[cur].z, qb[cur].w};

        float w[4][4];  // [hiA, loA, hiB, loB][j]
#pragma unroll
        for (int j = 0; j < 4; ++j) {
            w[0][j] = fmaf((float)((qsA[j] >> 4) & 0xF), ss[j], zs[j]);
            w[1][j] = fmaf((float)( qsA[j]       & 0xF), ss[j], zs[j]);
            w[2][j] = fmaf((float)((qsB[j] >> 4) & 0xF), ss[j], zs[j]);
            w[3][j] = fmaf((float)( qsB[j]       & 0xF), ss[j], zs[j]);
        }
#pragma unroll
        for (int b = 0; b < 8; ++b) {
            const float4 xb = *(const float4*)(xp + b * IN_ + it * 256);
#pragma unroll
            for (int r = 0; r < 4; ++r) {
                float a = acc[r][b];
                a = fmaf(xb.x, w[r][0], a);
                a = fmaf(xb.y, w[r][1], a);
                a = fmaf(xb.z, w[r][2], a);
                a = fmaf(xb.w, w[r][3], a);
                acc[r][b] = a;
            }
        }
    }

    // ---- single-wave LDS transpose reduce over the 64 K-slice lanes ----
    // write: per instruction o is uniform, addr = o*64 + perm(lane): conflict-
    // free. read: 2 lanes per output row, 8 x b128 each, slots spread by XOR.
#pragma unroll
    for (int r = 0; r < 4; ++r)
#pragma unroll
        for (int b = 0; b < 8; ++b) {
            const int o = r * 8 + b;
            red[o * 64 + (lane ^ ((o & 7) << 2))] = acc[r][b];
        }
    __syncthreads();                           // 1 wave: just a waitcnt

    const int o    = lane >> 1;                // 0..31 (= r*8 + b)
    const int half = lane & 1;
    const int cc   = (o & 7) << 2;
    float v = 0.f;
#pragma unroll
    for (int j = 0; j < 8; ++j) {
        const float4 t = *(const float4*)(red + o * 64 + half * 32 + ((j * 4) ^ cc));
        v += (t.x + t.y) + (t.z + t.w);
    }
    v += __shfl_down(v, 1, 64);
    if (half == 0)                             // 32 consecutive floats/wave
        ws[(c << 9) + (sib << 5) + o] = v;
}

__global__ void hqq_reduce(const float* __restrict__ ws,
                           const float* __restrict__ bias,
                           float* __restrict__ out) {
    // thread t = (oc, u): ws reads coalesced; scatter on the store side.
    const int t = blockIdx.x * 256 + threadIdx.x;  // 0 .. 172*512-1 = 88063
    if (t >= OC_ * 512) return;
    const int oc = t >> 9;                     // 0..171
    const int u  = t & 511;                    // sib*32 + r*8 + b
    const int base = (oc << 2 << 9) + u;       // chunk (oc, ks=0), slot u
    float v = 0.f;
#pragma unroll
    for (int k = 0; k < KS; ++k) v += ws[base + (k << 9)];
    const int sib = u >> 5;
    const int r   = (u >> 3) & 3;
    const int b   = u & 7;
    const int row = sib * 2 + (r >> 1) + (r & 1) * 32;
    const int oo  = row * OC_ + oc;
    out[b * OUT_ + oo] = v + bias[oo];
}

extern "C" void kernel_launch(void* const* d_in, const int* in_sizes, int n_in,
                              void* d_out, int out_size, void* d_ws, size_t ws_size,
                              hipStream_t stream) {
    const int*   Wq    = (const int*)d_in[0];    // [32, 704512] int32
    const float* scale = (const float*)d_in[1];  // [1, 704512]
    const float* zero  = (const float*)d_in[2];  // [1, 704512]
    const float* x     = (const float*)d_in[3];  // [8, 1, 4096]
    const float* bias  = (const float*)d_in[4];  // [11008]
    float* out = (float*)d_out;                  // [8, 1, 11008]
    float* ws  = (float*)d_ws;                   // 688*512 floats = 1.38 MB

    dim3 grid(NB);          // 11008 single-wave blocks, XCD-chunked
    dim3 block(64);
    hqq_gemv<<<grid, block, 0, stream>>>(Wq, scale, zero, x, ws);
    hqq_reduce<<<(OC_ * 512 + 255) / 256, 256, 0, stream>>>(ws, bias, out);
}